// Round 1
// baseline (105.386 us; speedup 1.0000x reference)
//
#include <hip/hip_runtime.h>
#include <math.h>

// Problem constants (match reference)
#define BATCH    8192
#define FIELDS   32
#define DIM      32
#define NREG     6
#define EPS      1e-5f

// ws layout (floats): [0..31] sum[f], [32..63] sumsq[f], [64..64+32*32) coef[f][d]

__global__ void irazor_init_kernel(const float* __restrict__ frw,   // [F, NREG]
                                   const float* __restrict__ mask,  // [NREG, DIM]
                                   float* __restrict__ ws) {
    const int t = threadIdx.x;
    if (t < 64) ws[t] = 0.0f;                 // zero stat accumulators
    __shared__ float smask[NREG * DIM];
    if (t < NREG * DIM) smask[t] = mask[t];
    __syncthreads();
    if (t < FIELDS) {
        float w[NREG];
        float m = -1e30f;
        #pragma unroll
        for (int r = 0; r < NREG; ++r) {
            w[r] = frw[t * NREG + r];
            m = fmaxf(m, w[r]);
        }
        float s = 0.0f;
        #pragma unroll
        for (int r = 0; r < NREG; ++r) { w[r] = __expf(w[r] - m); s += w[r]; }
        const float inv = 1.0f / s;
        for (int d = 0; d < DIM; ++d) {
            float c = 0.0f;
            #pragma unroll
            for (int r = 0; r < NREG; ++r) c += w[r] * smask[r * DIM + d];
            ws[64 + t * DIM + d] = c * inv;
        }
    }
}

// Per-field sum / sumsq over (batch, dim).
// grid = (BATCH/256, FIELDS), block = 256. 8 lanes per row (float4 each).
__global__ __launch_bounds__(256) void irazor_stats_kernel(
        const int* __restrict__ ids,     // [BATCH, FIELDS]
        const float* __restrict__ table, // [VOCAB, DIM]
        float* __restrict__ ws) {
    const int f    = blockIdx.y;
    const int b0   = blockIdx.x * 256;
    const int t    = threadIdx.x;
    const int rsub = t >> 3;   // 0..31: row within iteration
    const int vec  = t & 7;    // 0..7: which float4 of the 32-float row

    float s = 0.0f, sq = 0.0f;
    #pragma unroll
    for (int i = 0; i < 8; ++i) {
        const int b  = b0 + i * 32 + rsub;
        const int id = ids[b * FIELDS + f];
        const float4 v = *reinterpret_cast<const float4*>(
            table + (size_t)id * DIM + vec * 4);
        s  += v.x + v.y + v.z + v.w;
        sq += v.x * v.x + v.y * v.y + v.z * v.z + v.w * v.w;
    }

    // wave64 butterfly reduce
    #pragma unroll
    for (int off = 1; off < 64; off <<= 1) {
        s  += __shfl_xor(s, off);
        sq += __shfl_xor(sq, off);
    }
    __shared__ float ls[4], lq[4];
    const int wave = t >> 6;
    if ((t & 63) == 0) { ls[wave] = s; lq[wave] = sq; }
    __syncthreads();
    if (t == 0) {
        const float S  = ls[0] + ls[1] + ls[2] + ls[3];
        const float SQ = lq[0] + lq[1] + lq[2] + lq[3];
        atomicAdd(&ws[f], S);
        atomicAdd(&ws[32 + f], SQ);
    }
}

// Normalize + scale + write, natural [B,F,D] order (coalesced store).
__global__ __launch_bounds__(256) void irazor_out_kernel(
        const int* __restrict__ ids,
        const float* __restrict__ table,
        const float* __restrict__ ws,
        float* __restrict__ out) {
    const float* __restrict__ coef = ws + 64;
    const float invN = 1.0f / (float)(BATCH * DIM);
    const size_t total = (size_t)BATCH * FIELDS * (DIM / 4);  // float4 units
    for (size_t e = (size_t)blockIdx.x * blockDim.x + threadIdx.x; e < total;
         e += (size_t)gridDim.x * blockDim.x) {
        const int r   = (int)(e >> 3);        // row = b*F + f
        const int vec = (int)(e & 7);
        const int f   = r & (FIELDS - 1);
        const int id  = ids[r];
        const float4 v = *reinterpret_cast<const float4*>(
            table + (size_t)id * DIM + vec * 4);
        const float S    = ws[f];
        const float SQ   = ws[32 + f];
        const float mean = S * invN;
        const float var  = SQ * invN - mean * mean;
        const float istd = rsqrtf(var + EPS);
        const float4 c = *reinterpret_cast<const float4*>(coef + f * DIM + vec * 4);
        float4 o;
        o.x = (v.x - mean) * istd * c.x;
        o.y = (v.y - mean) * istd * c.y;
        o.z = (v.z - mean) * istd * c.z;
        o.w = (v.w - mean) * istd * c.w;
        reinterpret_cast<float4*>(out)[e] = o;
    }
}

extern "C" void kernel_launch(void* const* d_in, const int* in_sizes, int n_in,
                              void* d_out, int out_size, void* d_ws, size_t ws_size,
                              hipStream_t stream) {
    const int*   ids   = (const int*)d_in[0];    // [BATCH, FIELDS] int32
    const float* table = (const float*)d_in[1];  // [VOCAB, DIM] f32
    const float* frw   = (const float*)d_in[2];  // [FIELDS, NREG, 1] f32
    const float* mask  = (const float*)d_in[3];  // [NREG, DIM] f32
    float*       out   = (float*)d_out;
    float*       ws    = (float*)d_ws;

    irazor_init_kernel<<<1, 256, 0, stream>>>(frw, mask, ws);

    dim3 sgrid(BATCH / 256, FIELDS);
    irazor_stats_kernel<<<sgrid, 256, 0, stream>>>(ids, table, ws);

    irazor_out_kernel<<<2048, 256, 0, stream>>>(ids, table, ws, out);
}